// Round 11
// baseline (2362.406 us; speedup 1.0000x reference)
//
#include <hip/hip_runtime.h>
#include <hip/hip_bf16.h>
#include <hip/hip_cooperative_groups.h>
#include <math.h>

namespace cg = cooperative_groups;

#define BB 64
#define TT 256
#define CC 256
#define VV 65
#define LL 6
#define HH 8
#define BT (BB*TT)   // 16384

typedef unsigned short u16;
typedef __attribute__((ext_vector_type(8))) _Float16 h8v;
typedef __attribute__((ext_vector_type(4))) float f4v;
typedef __attribute__((ext_vector_type(4))) unsigned short u16x4;

typedef const unsigned int __attribute__((address_space(1))) gu32;
typedef unsigned int       __attribute__((address_space(3))) lu32;

__device__ inline u16 f2h(float f) { _Float16 h = (_Float16)f; return *(u16*)&h; }

__device__ inline void gld_lds16(const void* g, void* l) {
    __builtin_amdgcn_global_load_lds((gu32*)g, (lu32*)l, 16, 0, 0);
}

// Tiled operand format: [R,K] -> tiles [R/128][K/64], tile 16384 B fp16 swizzled:
// (r,k) at ushort r*64 + ((k>>3)^(r&7))*8 + (k&7).

#define E_QKV (LL*24*8192)
#define E_WO  (LL*8*8192)
#define E_W1  (LL*32*8192)
#define E_W2  (LL*32*8192)
#define E_LM  (4*8192)
#define E_QB  (LL*768)
#define E_TOT (E_QKV+E_WO+E_W1+E_W2+E_LM+E_QB)   // 4,755,968

struct MegaArgs {
    const int *idx, *tgt;
    const float *te, *pe, *wq, *bq, *wk, *bk, *wv, *bv, *wo, *bo;
    const float *ln1g, *ln1b, *w1, *b1, *w2, *b2, *ln2g, *ln2b, *lnfg, *lnfb, *lmw, *lmb;
    float* out;
    float* x; u16 *qkvh, *hiddenT, *xnT, *qkvT, *woT, *w1T, *w2T, *lmT; float* Bp;
};

__device__ void pack_dev(const float* __restrict__ src, u16* __restrict__ dst,
                         int K, int N, int NT, int KT, int id) {
    int perLayer = NT * KT * 8192;
    int l = id / perLayer; int rem = id - l * perLayer;
    int tile = rem >> 13, within = rem & 8191;
    int nT = tile / KT, kT = tile - nT * KT;
    int colIn = within >> 6, u = within & 63;
    int s = (u >> 3) ^ (colIn & 7);
    int k = kT * 64 + s * 8 + (u & 7);
    int n = nT * 128 + colIn;
    float v = (n < N) ? src[((size_t)l * K + k) * N + n] : 0.f;
    dst[((size_t)l * NT * KT + tile) * 8192 + within] = f2h(v);
}

__device__ void pack_one(int id, const MegaArgs& a) {
    if (id < E_QKV) {
        const int perLayer = 24 * 8192;
        int l = id / perLayer; int rem = id - l * perLayer;
        int tile = rem >> 13, within = rem & 8191;
        int nT = tile >> 2, kT = tile & 3;
        int colIn = within >> 6, u = within & 63;
        int s = (u >> 3) ^ (colIn & 7);
        int k = kT * 64 + s * 8 + (u & 7);
        int n = nT * 128 + colIn;
        int which = n >> 8, hd = n & 255, h = hd >> 5, d = hd & 31;
        const float* src = (which == 0) ? a.wq : (which == 1) ? a.wk : a.wv;
        float v = src[(((size_t)l * HH + h) * CC + k) * 32 + d];
        a.qkvT[((size_t)l * 24 + tile) * 8192 + within] = f2h(v);
        return;
    }
    id -= E_QKV;
    if (id < E_WO) { pack_dev(a.wo, a.woT, 256, 256, 2, 4, id); return; }
    id -= E_WO;
    if (id < E_W1) { pack_dev(a.w1, a.w1T, 256, 1024, 8, 4, id); return; }
    id -= E_W1;
    if (id < E_W2) { pack_dev(a.w2, a.w2T, 1024, 256, 2, 16, id); return; }
    id -= E_W2;
    if (id < E_LM) { pack_dev(a.lmw, a.lmT, 256, VV, 1, 4, id); return; }
    id -= E_LM;
    if (id < E_QB) {
        int l = id / 768, j = id % 768;
        int which = j >> 8, hd = j & 255, h = hd >> 5, d = hd & 31;
        const float* src = (which == 0) ? a.bq : (which == 1) ? a.bk : a.bv;
        a.Bp[id] = src[((size_t)l * HH + h) * 32 + d];
    }
}

// ---------------- LN stage: 2048 waves x 8 rows ----------------
__device__ void ln_stage(const float* __restrict__ x, const float* __restrict__ g,
                         const float* __restrict__ b, u16* __restrict__ outT,
                         int tid, int bid) {
    int lane = tid & 63;
    int gwave = bid * 8 + (tid >> 6);     // 0..2047
    float4 gv = ((const float4*)g)[lane];
    float4 bv = ((const float4*)b)[lane];
    int kT = lane >> 4;
    int kIn = (lane * 4) & 63;
    int slot = kIn >> 3, j = kIn & 7;
    #pragma unroll
    for (int i = 0; i < 8; ++i) {
        int row = i * 2048 + gwave;
        float4 v = ((const float4*)(x + (size_t)row * CC))[lane];
        float s = v.x + v.y + v.z + v.w;
        #pragma unroll
        for (int m = 1; m < 64; m <<= 1) s += __shfl_xor(s, m, 64);
        float mu = s * (1.f / CC);
        float dx = v.x - mu, dy = v.y - mu, dz = v.z - mu, dw = v.w - mu;
        float vs = dx * dx + dy * dy + dz * dz + dw * dw;
        #pragma unroll
        for (int m = 1; m < 64; m <<= 1) vs += __shfl_xor(vs, m, 64);
        float rs = rsqrtf(vs * (1.f / CC) + 1e-5f);
        int rIn = row & 127, mT = row >> 7;
        size_t base = ((size_t)mT * 4 + kT) * 8192;
        int ub = rIn * 64 + ((slot ^ (rIn & 7)) << 3) + j;
        u16x4 hv;
        hv[0] = f2h(dx * rs * gv.x + bv.x);
        hv[1] = f2h(dy * rs * gv.y + bv.y);
        hv[2] = f2h(dz * rs * gv.z + bv.z);
        hv[3] = f2h(dw * rs * gv.w + bv.w);
        *(u16x4*)(outT + base + ub) = hv;
    }
}

// ---------------- GEMM stage: BM=128 BN=128 BK=64, 8 waves, dbuf prefetch ------
// EPI 0: fp16 row-major + bias | 2: bias+relu tiled | 3: N=65 fp32 | 4: split-K atomicAdd
template<int EPI>
__device__ void gemm_stage(char* lds, const u16* __restrict__ At, const u16* __restrict__ Bt,
                           const float* __restrict__ bias, float* __restrict__ Co,
                           u16* __restrict__ CoT, int KTfull, int KTc, int NUNITS,
                           int NT, int N, int KTout, int tid, int bid) {
    int l = tid & 63, w = tid >> 6;
    int lrow = l & 15, lg = l >> 4;
    int wm = w >> 1, wn = w & 1;

    #define STAGE(buf, kt) {                                           \
        char* la = lds + (buf) * 32768 + w * 2048;                     \
        char* lb = lds + (buf) * 32768 + 16384 + w * 2048;             \
        const char* ga = Abase + (kt) * 16384 + w * 2048 + l * 16;     \
        const char* gb = Bbase + (kt) * 16384 + w * 2048 + l * 16;     \
        _Pragma("unroll")                                              \
        for (int jj = 0; jj < 2; ++jj) {                               \
            gld_lds16(ga + jj * 1024, la + jj * 1024);                 \
            gld_lds16(gb + jj * 1024, lb + jj * 1024);                 \
        } }

    for (int u = bid; u < NUNITS; u += 256) {
        int tileId = u, ktBase = 0;
        if (EPI == 4) {
            int ntile = NUNITS >> 1;
            if (u >= ntile) { tileId = u - ntile; ktBase = KTc; }
        }
        int mT = tileId / NT, nT = tileId - mT * NT;
        const char* Abase = (const char*)(At + ((size_t)mT * KTfull + ktBase) * 8192);
        const char* Bbase = (const char*)(Bt + ((size_t)nT * KTfull + ktBase) * 8192);

        f4v acc[2][4];
        #pragma unroll
        for (int i = 0; i < 2; ++i)
            #pragma unroll
            for (int j = 0; j < 4; ++j) acc[i][j] = (f4v)0.f;

        STAGE(0, 0);
        __syncthreads();
        int cur = 0;
        for (int kt = 0; kt < KTc; ++kt) {
            if (kt + 1 < KTc) STAGE(cur ^ 1, kt + 1);
            const char* lb0 = lds + cur * 32768;
            #pragma unroll
            for (int kh = 0; kh < 2; ++kh) {
                h8v ah[2], bh[4];
                #pragma unroll
                for (int mi = 0; mi < 2; ++mi) {
                    int rc = wm * 32 + mi * 16 + lrow;
                    ah[mi] = *(const h8v*)(lb0 + rc * 128 + 16 * ((kh * 4 + lg) ^ (rc & 7)));
                }
                #pragma unroll
                for (int ni = 0; ni < 4; ++ni) {
                    int rc = wn * 64 + ni * 16 + lrow;
                    bh[ni] = *(const h8v*)(lb0 + 16384 + rc * 128 + 16 * ((kh * 4 + lg) ^ (rc & 7)));
                }
                #pragma unroll
                for (int mi = 0; mi < 2; ++mi)
                    #pragma unroll
                    for (int ni = 0; ni < 4; ++ni)
                        acc[mi][ni] = __builtin_amdgcn_mfma_f32_16x16x32_f16(ah[mi], bh[ni], acc[mi][ni], 0, 0, 0);
            }
            __syncthreads();
            cur ^= 1;
        }

        int colbase = nT * 128 + wn * 64;
        if (EPI == 0) {
            #pragma unroll
            for (int mi = 0; mi < 2; ++mi) {
                int r0 = mT * 128 + wm * 32 + mi * 16 + lg * 4;
                #pragma unroll
                for (int ni = 0; ni < 4; ++ni) {
                    int cg = colbase + ni * 16 + lrow;
                    float bv = bias[cg];
                    #pragma unroll
                    for (int q = 0; q < 4; ++q)
                        CoT[(size_t)(r0 + q) * N + cg] = f2h(acc[mi][ni][q] + bv);
                }
            }
        } else if (EPI == 2) {
            #pragma unroll
            for (int mi = 0; mi < 2; ++mi) {
                int r0 = mT * 128 + wm * 32 + mi * 16 + lg * 4;
                #pragma unroll
                for (int ni = 0; ni < 4; ++ni) {
                    int cg = colbase + ni * 16 + lrow;
                    float bv = bias[cg];
                    int kTo = cg >> 6, kIn = cg & 63;
                    size_t tbase = ((size_t)mT * KTout + kTo) * 8192;
                    #pragma unroll
                    for (int q = 0; q < 4; ++q) {
                        int rIn = (r0 + q) & 127;
                        float f = fmaxf(acc[mi][ni][q] + bv, 0.f);
                        int ub = rIn * 64 + (((kIn >> 3) ^ (rIn & 7)) << 3) + (kIn & 7);
                        CoT[tbase + ub] = f2h(f);
                    }
                }
            }
        } else if (EPI == 3) {
            #pragma unroll
            for (int mi = 0; mi < 2; ++mi) {
                int r0 = mT * 128 + wm * 32 + mi * 16 + lg * 4;
                #pragma unroll
                for (int ni = 0; ni < 4; ++ni) {
                    int cg = colbase + ni * 16 + lrow;
                    if (cg < VV) {
                        float bv = bias[cg];
                        #pragma unroll
                        for (int q = 0; q < 4; ++q)
                            Co[(size_t)(r0 + q) * VV + cg] = acc[mi][ni][q] + bv;
                    }
                }
            }
        } else {
            #pragma unroll
            for (int mi = 0; mi < 2; ++mi) {
                int r0 = mT * 128 + wm * 32 + mi * 16 + lg * 4;
                #pragma unroll
                for (int ni = 0; ni < 4; ++ni) {
                    int cg = colbase + ni * 16 + lrow;
                    float bv = (ktBase == 0) ? bias[cg] : 0.f;
                    #pragma unroll
                    for (int q = 0; q < 4; ++q)
                        atomicAdd(Co + (size_t)(r0 + q) * N + cg, acc[mi][ni][q] + bv);
                }
            }
        }
    }
    #undef STAGE
}

// ---------------- attention stage: 512 units over 256 blocks, 8 waves ----------
// LDS: K [256][80B] @0 ; V^T [32][528B] @20480 ; P/wave [16][80B] @37376+w*1280.
__device__ void attn_stage(char* lds, const u16* __restrict__ qkv,
                           u16* __restrict__ outT, int tid, int bid) {
    int w = tid >> 6, l = tid & 63;
    int li = l & 15, g = l >> 4;
    for (int u = bid; u < 512; u += 256) {
        int bb = u >> 3, h = u & 7;
        const u16* base = qkv + (size_t)bb * TT * 768;
        __syncthreads();                        // protect LDS reuse across units
        {
            int r0 = tid >> 3, c = tid & 7;     // 64 rows/iter with 512 threads
            #pragma unroll
            for (int it = 0; it < 4; ++it) {
                int t = it * 64 + r0;
                u16x4 kv = *(const u16x4*)(base + (size_t)t * 768 + 256 + h * 32 + c * 4);
                u16x4 vv = *(const u16x4*)(base + (size_t)t * 768 + 512 + h * 32 + c * 4);
                *(u16x4*)(lds + t * 80 + c * 8) = kv;
                *(u16*)(lds + 20480 + (c * 4 + 0) * 528 + t * 2) = vv[0];
                *(u16*)(lds + 20480 + (c * 4 + 1) * 528 + t * 2) = vv[1];
                *(u16*)(lds + 20480 + (c * 4 + 2) * 528 + t * 2) = vv[2];
                *(u16*)(lds + 20480 + (c * 4 + 3) * 528 + t * 2) = vv[3];
            }
        }
        __syncthreads();

        char* Pb = lds + 37376 + w * 1280;
        int mts[2] = {w, 15 - w};               // balanced: 9 kv-units per wave
        #pragma unroll
        for (int im = 0; im < 2; ++im) {
            int mt = mts[im];
            int mq = mt * 16;
            h8v aq = *(const h8v*)(base + (size_t)(mq + li) * 768 + h * 32 + g * 8);

            f4v o0 = (f4v)0.f, o1 = (f4v)0.f;
            float mrun0 = -1e30f, mrun1 = -1e30f, mrun2 = -1e30f, mrun3 = -1e30f;
            float lrun0 = 0.f, lrun1 = 0.f, lrun2 = 0.f, lrun3 = 0.f;
            int nu = (mt >> 1) + 1;
            for (int kt = 0; kt < nu; ++kt) {
                int kb = kt * 32;
                h8v kf0 = *(const h8v*)(lds + (kb + li) * 80 + g * 16);
                h8v kf1 = *(const h8v*)(lds + (kb + 16 + li) * 80 + g * 16);
                f4v s0 = __builtin_amdgcn_mfma_f32_16x16x32_f16(aq, kf0, (f4v)0.f, 0, 0, 0);
                f4v s1 = __builtin_amdgcn_mfma_f32_16x16x32_f16(aq, kf1, (f4v)0.f, 0, 0, 0);
                bool maskunit = (kt == nu - 1);
                float p0[4], p1[4];
                float* mr[4] = {&mrun0, &mrun1, &mrun2, &mrun3};
                float* lr[4] = {&lrun0, &lrun1, &lrun2, &lrun3};
                #pragma unroll
                for (int qq = 0; qq < 4; ++qq) {
                    float v0 = s0[qq] * 0.0625f;     // scale = C^-0.5 = 1/16
                    float v1 = s1[qq] * 0.0625f;
                    if (maskunit) {
                        int qg = mq + g * 4 + qq;
                        if (kb + li > qg)      v0 = -1e30f;
                        if (kb + 16 + li > qg) v1 = -1e30f;
                    }
                    float tm = fmaxf(v0, v1);
                    #pragma unroll
                    for (int msk = 1; msk < 16; msk <<= 1)
                        tm = fmaxf(tm, __shfl_xor(tm, msk, 64));
                    float mold = *mr[qq];
                    float mnew = fmaxf(mold, tm);
                    float corr = __expf(mold - mnew);
                    float e0 = __expf(v0 - mnew);
                    float e1 = __expf(v1 - mnew);
                    float ts = e0 + e1;
                    #pragma unroll
                    for (int msk = 1; msk < 16; msk <<= 1)
                        ts += __shfl_xor(ts, msk, 64);
                    *lr[qq] = *lr[qq] * corr + ts;
                    *mr[qq] = mnew;
                    o0[qq] *= corr; o1[qq] *= corr;
                    p0[qq] = e0; p1[qq] = e1;
                }
                #pragma unroll
                for (int qq = 0; qq < 4; ++qq) {
                    *(u16*)(Pb + (g * 4 + qq) * 80 + li * 2)        = f2h(p0[qq]);
                    *(u16*)(Pb + (g * 4 + qq) * 80 + (16 + li) * 2) = f2h(p1[qq]);
                }
                h8v pf  = *(const h8v*)(Pb + li * 80 + g * 16);
                h8v vf0 = *(const h8v*)(lds + 20480 + li * 528        + kb * 2 + g * 16);
                h8v vf1 = *(const h8v*)(lds + 20480 + (16 + li) * 528 + kb * 2 + g * 16);
                o0 = __builtin_amdgcn_mfma_f32_16x16x32_f16(pf, vf0, o0, 0, 0, 0);
                o1 = __builtin_amdgcn_mfma_f32_16x16x32_f16(pf, vf1, o1, 0, 0, 0);
            }
            float invs[4] = {1.f / lrun0, 1.f / lrun1, 1.f / lrun2, 1.f / lrun3};
            #pragma unroll
            for (int qq = 0; qq < 4; ++qq) {
                int tok = mq + g * 4 + qq;
                int rIn = tok & 127;
                size_t tb = ((size_t)(bb * 2 + (tok >> 7)) * 4 + (h >> 1)) * 8192;
                float f0 = o0[qq] * invs[qq];
                float f1 = o1[qq] * invs[qq];
                int kIn0 = (h & 1) * 32 + li;
                int kIn1 = kIn0 + 16;
                int ub0 = rIn * 64 + (((kIn0 >> 3) ^ (rIn & 7)) << 3) + (kIn0 & 7);
                int ub1 = rIn * 64 + (((kIn1 >> 3) ^ (rIn & 7)) << 3) + (kIn1 & 7);
                outT[tb + ub0] = f2h(f0);
                outT[tb + ub1] = f2h(f1);
            }
        }
    }
}

// ---------------- loss stage ----------------
__device__ void loss_stage(const float* __restrict__ lg, const int* __restrict__ tgt,
                           float* __restrict__ loss, int gtid) {
    float nl = 0.f;
    if (gtid < BT) {
        const float* r = lg + (size_t)gtid * VV;
        float mx = -INFINITY;
        for (int v = 0; v < VV; ++v) mx = fmaxf(mx, r[v]);
        float se = 0.f;
        for (int v = 0; v < VV; ++v) se += __expf(r[v] - mx);
        nl = mx + __logf(se) - r[tgt[gtid]];
    }
    #pragma unroll
    for (int m = 1; m < 64; m <<= 1) nl += __shfl_xor(nl, m, 64);
    if ((gtid & 63) == 0 && gtid < BT)
        atomicAdd(loss, nl * (1.f / BT));
}

// ---------------- the megakernel ----------------
__global__ __launch_bounds__(512, 2)
void mega(MegaArgs a) {
    __shared__ __align__(16) char lds[65536];
    cg::grid_group grid = cg::this_grid();
    int tid = threadIdx.x, bid = blockIdx.x;
    int gtid = bid * 512 + tid;

    // S0: pack all weights + embedding + zero loss slot
    for (int e = gtid; e < E_TOT; e += 131072) pack_one(e, a);
    for (int i = gtid; i < BT * 64; i += 131072) {
        int bt = i >> 6, c4 = i & 63;
        int tok = a.idx[bt];
        int t = bt & (TT - 1);
        float4 av = ((const float4*)a.te)[(size_t)tok * 64 + c4];
        float4 p = ((const float4*)a.pe)[(size_t)t * 64 + c4];
        float4 o; o.x = av.x + p.x; o.y = av.y + p.y; o.z = av.z + p.z; o.w = av.w + p.w;
        ((float4*)a.x)[i] = o;
    }
    if (gtid == 0) a.out[(size_t)BT * VV] = 0.f;
    grid.sync();

    for (int l = 0; l < LL; ++l) {
        ln_stage(a.x, a.ln1g + l * CC, a.ln1b + l * CC, a.xnT, tid, bid);
        grid.sync();
        gemm_stage<0>(lds, a.xnT, a.qkvT + (size_t)l * 196608, a.Bp + l * 768,
                      nullptr, a.qkvh, 4, 4, 768, 6, 768, 0, tid, bid);
        grid.sync();
        attn_stage(lds, a.qkvh, a.xnT, tid, bid);
        grid.sync();
        gemm_stage<4>(lds, a.xnT, a.woT + (size_t)l * 65536, a.bo + l * CC,
                      a.x, nullptr, 4, 2, 512, 2, 256, 0, tid, bid);
        grid.sync();
        ln_stage(a.x, a.ln2g + l * CC, a.ln2b + l * CC, a.xnT, tid, bid);
        grid.sync();
        gemm_stage<2>(lds, a.xnT, a.w1T + (size_t)l * 262144, a.b1 + l * 1024,
                      nullptr, a.hiddenT, 4, 4, 1024, 8, 1024, 16, tid, bid);
        grid.sync();
        gemm_stage<4>(lds, a.hiddenT, a.w2T + (size_t)l * 262144, a.b2 + l * CC,
                      a.x, nullptr, 16, 8, 512, 2, 256, 0, tid, bid);
        grid.sync();
    }
    ln_stage(a.x, a.lnfg, a.lnfb, a.xnT, tid, bid);
    grid.sync();
    gemm_stage<3>(lds, a.xnT, a.lmT, a.lmb, a.out, nullptr, 4, 4, 128, 1, VV, 0, tid, bid);
    grid.sync();
    loss_stage(a.out, a.tgt, a.out + (size_t)BT * VV, gtid);
}

extern "C" void kernel_launch(void* const* d_in, const int* in_sizes, int n_in,
                              void* d_out, int out_size, void* d_ws, size_t ws_size,
                              hipStream_t stream) {
    char* base = (char*)d_ws;
    MegaArgs a;
    a.idx  = (const int*)d_in[0];
    a.tgt  = (const int*)d_in[1];
    a.te   = (const float*)d_in[2];
    a.pe   = (const float*)d_in[3];
    a.wq   = (const float*)d_in[4];
    a.bq   = (const float*)d_in[5];
    a.wk   = (const float*)d_in[6];
    a.bk   = (const float*)d_in[7];
    a.wv   = (const float*)d_in[8];
    a.bv   = (const float*)d_in[9];
    a.wo   = (const float*)d_in[10];
    a.bo   = (const float*)d_in[11];
    a.ln1g = (const float*)d_in[12];
    a.ln1b = (const float*)d_in[13];
    a.w1   = (const float*)d_in[14];
    a.b1   = (const float*)d_in[15];
    a.w2   = (const float*)d_in[16];
    a.b2   = (const float*)d_in[17];
    a.ln2g = (const float*)d_in[18];
    a.ln2b = (const float*)d_in[19];
    a.lnfg = (const float*)d_in[20];
    a.lnfb = (const float*)d_in[21];
    a.lmw  = (const float*)d_in[22];
    a.lmb  = (const float*)d_in[23];
    a.out  = (float*)d_out;
    a.x       = (float*)(base);                 // 16 MB fp32 residual
    a.qkvh    = (u16*)  (base + (16ll << 20));  // 24 MB fp16 [16384][768]
    a.hiddenT = (u16*)  (base + (40ll << 20));  // 32 MB fp16 tiled
    a.xnT     = (u16*)  (base + (72ll << 20));  //  8 MB fp16 tiled
    a.qkvT    = (u16*)  (base + (80ll << 20));
    a.woT     = (u16*)  (base + (83ll << 20));
    a.w1T     = (u16*)  (base + (84ll << 20));
    a.w2T     = (u16*)  (base + (87ll << 20));
    a.lmT     = (u16*)  (base + (90ll << 20));
    a.Bp      = (float*)(base + (91ll << 20));

    void* kargs[] = { (void*)&a };
    hipLaunchCooperativeKernel(mega, dim3(256), dim3(512), kargs, 0, stream);
}

// Round 12
// 816.691 us; speedup vs baseline: 2.8927x; 2.8927x over previous
//
#include <hip/hip_runtime.h>
#include <hip/hip_bf16.h>
#include <math.h>

#define BB 64
#define TT 256
#define CC 256
#define VV 65
#define LL 6
#define HH 8
#define BT (BB*TT)   // 16384

typedef unsigned short u16;
typedef __attribute__((ext_vector_type(8))) _Float16 h8v;   // 8 fp16 (4 VGPRs)
typedef __attribute__((ext_vector_type(4))) float f4v;      // MFMA acc
typedef __attribute__((ext_vector_type(4))) unsigned short u16x4;

typedef const unsigned int __attribute__((address_space(1))) gu32;
typedef unsigned int       __attribute__((address_space(3))) lu32;

__device__ inline u16 f2h(float f) { _Float16 h = (_Float16)f; return *(u16*)&h; }

__device__ inline void gld_lds16(const void* g, void* l) {
    __builtin_amdgcn_global_load_lds((gu32*)g, (lu32*)l, 16, 0, 0);
}

// Tiled operand format: matrix [R, K] -> tiles [R/128][K/64]; tile = 16384 B
// fp16, swizzled: element (r,k) at ushort index r*64 + ((k>>3)^(r&7))*8 + (k&7).

// ---------------- one-shot pack of ALL weights ----------------
__device__ inline void pack_dev(const float* __restrict__ src, u16* __restrict__ dst,
                                int K, int N, int NT, int KT, int id) {
    int perLayer = NT * KT * 8192;
    int l = id / perLayer; int rem = id - l * perLayer;
    int tile = rem >> 13, within = rem & 8191;
    int nT = tile / KT, kT = tile - nT * KT;
    int colIn = within >> 6, u = within & 63;
    int s = (u >> 3) ^ (colIn & 7);
    int k = kT * 64 + s * 8 + (u & 7);
    int n = nT * 128 + colIn;
    float v = (n < N) ? src[((size_t)l * K + k) * N + n] : 0.f;
    dst[((size_t)l * NT * KT + tile) * 8192 + within] = f2h(v);
}

#define E_QKV (LL*24*8192)
#define E_WO  (LL*8*8192)
#define E_W1  (LL*32*8192)
#define E_W2  (LL*32*8192)
#define E_LM  (4*8192)
#define E_QB  (LL*768)
#define E_TOT (E_QKV+E_WO+E_W1+E_W2+E_LM+E_QB)   // 4,755,968 = 256*18578

__global__ __launch_bounds__(256)
void pack_all(const float* __restrict__ wq, const float* __restrict__ wk,
              const float* __restrict__ wv, const float* __restrict__ wo,
              const float* __restrict__ w1, const float* __restrict__ w2,
              const float* __restrict__ lmw,
              const float* __restrict__ bq, const float* __restrict__ bk,
              const float* __restrict__ bv,
              u16* __restrict__ qkvT, u16* __restrict__ woT, u16* __restrict__ w1T,
              u16* __restrict__ w2T, u16* __restrict__ lmT, float* __restrict__ Bp) {
    int id = blockIdx.x * 256 + threadIdx.x;
    if (id < E_QKV) {
        const int perLayer = 24 * 8192;
        int l = id / perLayer; int rem = id - l * perLayer;
        int tile = rem >> 13, within = rem & 8191;
        int nT = tile >> 2, kT = tile & 3;
        int colIn = within >> 6, u = within & 63;
        int s = (u >> 3) ^ (colIn & 7);
        int k = kT * 64 + s * 8 + (u & 7);
        int n = nT * 128 + colIn;
        int which = n >> 8, hd = n & 255, h = hd >> 5, d = hd & 31;
        const float* src = (which == 0) ? wq : (which == 1) ? wk : wv;
        float v = src[(((size_t)l * HH + h) * CC + k) * 32 + d];
        qkvT[((size_t)l * 24 + tile) * 8192 + within] = f2h(v);
        return;
    }
    id -= E_QKV;
    if (id < E_WO) { pack_dev(wo, woT, 256, 256, 2, 4, id); return; }
    id -= E_WO;
    if (id < E_W1) { pack_dev(w1, w1T, 256, 1024, 8, 4, id); return; }
    id -= E_W1;
    if (id < E_W2) { pack_dev(w2, w2T, 1024, 256, 2, 16, id); return; }
    id -= E_W2;
    if (id < E_LM) { pack_dev(lmw, lmT, 256, VV, 1, 4, id); return; }
    id -= E_LM;
    if (id < E_QB) {
        int l = id / 768, j = id % 768;
        int which = j >> 8, hd = j & 255, h = hd >> 5, d = hd & 31;
        const float* src = (which == 0) ? bq : (which == 1) ? bk : bv;
        Bp[id] = src[((size_t)l * HH + h) * 32 + d];
    }
}

// ---------------- embedding ----------------
__global__ __launch_bounds__(256)
void embed_kernel(const int* __restrict__ idx, const float* __restrict__ te,
                  const float* __restrict__ pe, float* __restrict__ x) {
    int i = blockIdx.x * blockDim.x + threadIdx.x;
    if (i >= BT * 64) return;
    int bt = i >> 6, c4 = i & 63;
    int tok = idx[bt];
    int t = bt & (TT - 1);
    float4 a = ((const float4*)te)[(size_t)tok * 64 + c4];
    float4 p = ((const float4*)pe)[(size_t)t * 64 + c4];
    float4 o; o.x = a.x + p.x; o.y = a.y + p.y; o.z = a.z + p.z; o.w = a.w + p.w;
    ((float4*)x)[i] = o;
}

// ---------------- LN core (shared by ln_kernel / sum_ln) ----------------
__device__ inline void ln_emit(float4 v, const float* __restrict__ g,
                               const float* __restrict__ b, u16* __restrict__ outT,
                               int row, int lane) {
    float s = v.x + v.y + v.z + v.w;
    #pragma unroll
    for (int m = 1; m < 64; m <<= 1) s += __shfl_xor(s, m, 64);
    float mu = s * (1.f / CC);
    float dx = v.x - mu, dy = v.y - mu, dz = v.z - mu, dw = v.w - mu;
    float vs = dx * dx + dy * dy + dz * dz + dw * dw;
    #pragma unroll
    for (int m = 1; m < 64; m <<= 1) vs += __shfl_xor(vs, m, 64);
    float rs = rsqrtf(vs * (1.f / CC) + 1e-5f);
    float4 gv = ((const float4*)g)[lane];
    float4 bv = ((const float4*)b)[lane];
    int rIn = row & 127, mT = row >> 7;
    int kT = lane >> 4;
    int kIn = (lane * 4) & 63;
    int slot = kIn >> 3, j = kIn & 7;
    size_t base = ((size_t)mT * 4 + kT) * 8192;
    int ub = rIn * 64 + ((slot ^ (rIn & 7)) << 3) + j;
    u16x4 hv;
    hv[0] = f2h(dx * rs * gv.x + bv.x);
    hv[1] = f2h(dy * rs * gv.y + bv.y);
    hv[2] = f2h(dz * rs * gv.z + bv.z);
    hv[3] = f2h(dw * rs * gv.w + bv.w);
    *(u16x4*)(outT + base + ub) = hv;
}

// plain LN (layer-0 ln1): x already complete
__global__ __launch_bounds__(256)
void ln_kernel(const float* __restrict__ x, const float* __restrict__ g,
               const float* __restrict__ b, u16* __restrict__ outT) {
    int lane = threadIdx.x & 63;
    int row = blockIdx.x * 4 + (threadIdx.x >> 6);
    float4 v = ((const float4*)(x + (size_t)row * CC))[lane];
    ln_emit(v, g, b, outT, row, lane);
}

// fused: xs = x + p0 + p1 + gemm_bias; x <- xs; outT <- LN(xs) tiled
__global__ __launch_bounds__(256)
void sum_ln(float* __restrict__ x, const float* __restrict__ p0,
            const float* __restrict__ p1, const float* __restrict__ gbias,
            const float* __restrict__ g, const float* __restrict__ b,
            u16* __restrict__ outT) {
    int lane = threadIdx.x & 63;
    int row = blockIdx.x * 4 + (threadIdx.x >> 6);
    size_t off = (size_t)row * CC;
    float4 v  = ((const float4*)(x + off))[lane];
    float4 a0 = ((const float4*)(p0 + off))[lane];
    float4 a1 = ((const float4*)(p1 + off))[lane];
    float4 bb = ((const float4*)gbias)[lane];
    v.x += a0.x + a1.x + bb.x;
    v.y += a0.y + a1.y + bb.y;
    v.z += a0.z + a1.z + bb.z;
    v.w += a0.w + a1.w + bb.w;
    ((float4*)(x + off))[lane] = v;
    ln_emit(v, g, b, outT, row, lane);
}

// ---------------- MFMA GEMM: C[16384,N] = A @ W (A,B tiled fp16) --------------
// BM=128 BN=128 BK=64, 512 thr = 8 waves (4x2, wave tile 32x64), dbuf prefetch.
// EPI 0: fp16 row-major + bias | 2: bias+relu -> tiled fp16 | 3: N=65 fp32
// EPI 4: split-K partial -> plain fp32 store into Co + blockIdx.y*BT*N (no bias)
template<int EPI>
__global__ __launch_bounds__(512, 4)
void gemm_mfma(const u16* __restrict__ At, const u16* __restrict__ Bt,
               const float* __restrict__ bias, float* __restrict__ Co,
               u16* __restrict__ CoT, int KTfull, int KTc, int NT, int N, int KTout) {
    __shared__ __align__(16) char lds[65536];   // 2 bufs x (A 16K + B 16K)
    int tid = threadIdx.x;
    int l = tid & 63, w = tid >> 6;             // 8 waves
    int nwg = gridDim.x;
    int id = blockIdx.x;
    int cpx = nwg >> 3;                          // all grids %8==0
    id = (id & 7) * cpx + (id >> 3);             // XCD-contiguous chunks
    int mT = id / NT, nT = id - mT * NT;
    int ktBase = blockIdx.y * KTc;

    const char* Abase = (const char*)(At + ((size_t)mT * KTfull + ktBase) * 8192);
    const char* Bbase = (const char*)(Bt + ((size_t)nT * KTfull + ktBase) * 8192);
    int wm = w >> 1, wn = w & 1;                 // wave tile: rows [wm*32,+32), cols [wn*64,+64)

    f4v acc[2][4];
    #pragma unroll
    for (int i = 0; i < 2; ++i)
        #pragma unroll
        for (int j = 0; j < 4; ++j) acc[i][j] = (f4v)0.f;

    int lrow = l & 15, lg = l >> 4;

    #define STAGE(buf, kt) {                                           \
        char* la = lds + (buf) * 32768 + w * 2048;                     \
        char* lb = lds + (buf) * 32768 + 16384 + w * 2048;             \
        const char* ga = Abase + (kt) * 16384 + w * 2048 + l * 16;     \
        const char* gb = Bbase + (kt) * 16384 + w * 2048 + l * 16;     \
        _Pragma("unroll")                                              \
        for (int j = 0; j < 2; ++j) {                                  \
            gld_lds16(ga + j * 1024, la + j * 1024);                   \
            gld_lds16(gb + j * 1024, lb + j * 1024);                   \
        } }

    STAGE(0, 0);
    __syncthreads();
    int cur = 0;
    for (int kt = 0; kt < KTc; ++kt) {
        if (kt + 1 < KTc) STAGE(cur ^ 1, kt + 1);   // prefetch overlaps compute
        const char* lb0 = lds + cur * 32768;
        #pragma unroll
        for (int kh = 0; kh < 2; ++kh) {
            h8v ah[2], bh[4];
            #pragma unroll
            for (int mi = 0; mi < 2; ++mi) {
                int rc = wm * 32 + mi * 16 + lrow;
                ah[mi] = *(const h8v*)(lb0 + rc * 128 + 16 * ((kh * 4 + lg) ^ (rc & 7)));
            }
            #pragma unroll
            for (int ni = 0; ni < 4; ++ni) {
                int rc = wn * 64 + ni * 16 + lrow;
                bh[ni] = *(const h8v*)(lb0 + 16384 + rc * 128 + 16 * ((kh * 4 + lg) ^ (rc & 7)));
            }
            #pragma unroll
            for (int mi = 0; mi < 2; ++mi)
                #pragma unroll
                for (int ni = 0; ni < 4; ++ni)
                    acc[mi][ni] = __builtin_amdgcn_mfma_f32_16x16x32_f16(ah[mi], bh[ni], acc[mi][ni], 0, 0, 0);
        }
        __syncthreads();
        cur ^= 1;
    }
    #undef STAGE

    // epilogue: C frag col = l&15, row = (l>>4)*4 + q  [m89-verified]
    int colbase = nT * 128 + wn * 64;
    if (EPI == 0) {          // fp16 row-major [16384][N] + bias
        #pragma unroll
        for (int mi = 0; mi < 2; ++mi) {
            int r0 = mT * 128 + wm * 32 + mi * 16 + lg * 4;
            #pragma unroll
            for (int ni = 0; ni < 4; ++ni) {
                int cg = colbase + ni * 16 + lrow;
                float bv = bias[cg];
                #pragma unroll
                for (int q = 0; q < 4; ++q)
                    CoT[(size_t)(r0 + q) * N + cg] = f2h(acc[mi][ni][q] + bv);
            }
        }
    } else if (EPI == 2) {   // bias + relu -> tiled fp16
        #pragma unroll
        for (int mi = 0; mi < 2; ++mi) {
            int r0 = mT * 128 + wm * 32 + mi * 16 + lg * 4;
            #pragma unroll
            for (int ni = 0; ni < 4; ++ni) {
                int cg = colbase + ni * 16 + lrow;
                float bv = bias[cg];
                int kTo = cg >> 6, kIn = cg & 63;
                size_t tbase = ((size_t)mT * KTout + kTo) * 8192;
                #pragma unroll
                for (int q = 0; q < 4; ++q) {
                    int rIn = (r0 + q) & 127;
                    float f = fmaxf(acc[mi][ni][q] + bv, 0.f);
                    int ub = rIn * 64 + (((kIn >> 3) ^ (rIn & 7)) << 3) + (kIn & 7);
                    CoT[tbase + ub] = f2h(f);
                }
            }
        }
    } else if (EPI == 3) {   // lm head fp32 [16384][65]
        #pragma unroll
        for (int mi = 0; mi < 2; ++mi) {
            int r0 = mT * 128 + wm * 32 + mi * 16 + lg * 4;
            #pragma unroll
            for (int ni = 0; ni < 4; ++ni) {
                int cg = colbase + ni * 16 + lrow;
                if (cg < VV) {
                    float bv = bias[cg];
                    #pragma unroll
                    for (int q = 0; q < 4; ++q)
                        Co[(size_t)(r0 + q) * VV + cg] = acc[mi][ni][q] + bv;
                }
            }
        }
    } else {                 // EPI 4: plain fp32 partial store (no bias, no atomic)
        float* P = Co + (size_t)blockIdx.y * ((size_t)BT * N);
        #pragma unroll
        for (int mi = 0; mi < 2; ++mi) {
            int r0 = mT * 128 + wm * 32 + mi * 16 + lg * 4;
            #pragma unroll
            for (int ni = 0; ni < 4; ++ni) {
                int cg = colbase + ni * 16 + lrow;
                #pragma unroll
                for (int q = 0; q < 4; ++q)
                    P[(size_t)(r0 + q) * N + cg] = acc[mi][ni][q];
            }
        }
    }
}

// ---------------- MFMA flash attention: block per (b,h), 4 waves ----------------
// qkv input fp16 row-major [16384][768].
// LDS: K fp16 [256][80B] @0 ; V^T fp16 [32][528B] @20480 ; P/wave [16][80B] @37376+w*1280.
__global__ __launch_bounds__(256)
void attn_mfma(const u16* __restrict__ qkv, u16* __restrict__ outT) {
    __shared__ __align__(16) char lds[42496];
    int bh = blockIdx.x;
    bh = (bh & 7) * 64 + (bh >> 3);      // bijective XCD swizzle (512 = 8*64)
    int b = bh >> 3, h = bh & 7;
    const u16* base = qkv + (size_t)b * TT * 768;
    int tid = threadIdx.x;
    int w = tid >> 6, l = tid & 63;
    int li = l & 15, g = l >> 4;

    {
        int r0 = tid >> 3, c = tid & 7;
        #pragma unroll
        for (int it = 0; it < 8; ++it) {
            int t = it * 32 + r0;
            u16x4 kv = *(const u16x4*)(base + (size_t)t * 768 + 256 + h * 32 + c * 4);
            u16x4 vv = *(const u16x4*)(base + (size_t)t * 768 + 512 + h * 32 + c * 4);
            *(u16x4*)(lds + t * 80 + c * 8) = kv;
            *(u16*)(lds + 20480 + (c * 4 + 0) * 528 + t * 2) = vv[0];
            *(u16*)(lds + 20480 + (c * 4 + 1) * 528 + t * 2) = vv[1];
            *(u16*)(lds + 20480 + (c * 4 + 2) * 528 + t * 2) = vv[2];
            *(u16*)(lds + 20480 + (c * 4 + 3) * 528 + t * 2) = vv[3];
        }
    }
    __syncthreads();

    char* Pb = lds + 37376 + w * 1280;
    int mts[4] = {w, 7 - w, 8 + w, 15 - w};
    #pragma unroll
    for (int im = 0; im < 4; ++im) {
        int mt = mts[im];
        int mq = mt * 16;
        h8v aq = *(const h8v*)(base + (size_t)(mq + li) * 768 + h * 32 + g * 8);

        f4v o0 = (f4v)0.f, o1 = (f4v)0.f;
        float mrun0 = -1e30f, mrun1 = -1e30f, mrun2 = -1e30f, mrun3 = -1e30f;
        float lrun0 = 0.f, lrun1 = 0.f, lrun2 = 0.f, lrun3 = 0.f;
        int nu = (mt >> 1) + 1;
        for (int kt = 0; kt < nu; ++kt) {
            int kb = kt * 32;
            h8v kf0 = *(const h8v*)(lds + (kb + li) * 80 + g * 16);
            h8v kf1 = *(const h8v*)(lds + (kb + 16 + li) * 80 + g * 16);
            f4v s0 = __builtin_amdgcn_mfma_f32_16x16x32_f16(aq, kf0, (f4v)0.f, 0, 0, 0);
            f4v s1 = __builtin_amdgcn_mfma_f32_16x16x32_f16(aq, kf1, (f4v)0.f, 0, 0, 0);
            bool maskunit = (kt == nu - 1);
            float p0[4], p1[4];
            float* mr[4] = {&mrun0, &mrun1, &mrun2, &mrun3};
            float* lr[4] = {&lrun0, &lrun1, &lrun2, &lrun3};
            #pragma unroll
            for (int qq = 0; qq < 4; ++qq) {
                float v0 = s0[qq] * 0.0625f;     // scale = C^-0.5 = 1/16
                float v1 = s1[qq] * 0.0625f;
                if (maskunit) {
                    int qg = mq + g * 4 + qq;
                    if (kb + li > qg)      v0 = -1e30f;
                    if (kb + 16 + li > qg) v1 = -1e30f;
                }
                float tm = fmaxf(v0, v1);
                #pragma unroll
                for (int msk = 1; msk < 16; msk <<= 1)
                    tm = fmaxf(tm, __shfl_xor(tm, msk, 64));
                float mold = *mr[qq];
                float mnew = fmaxf(mold, tm);
                float corr = __expf(mold - mnew);
                float e0 = __expf(v0 - mnew);
                float e1 = __expf(v1 - mnew);
                float ts = e0 + e1;
                #pragma unroll
                for (int msk = 1; msk < 16; msk <<= 1)
                    ts += __shfl_xor(ts, msk, 64);
                *lr[qq] = *lr[qq] * corr + ts;
                *mr[qq] = mnew;
                o0[qq] *= corr; o1[qq] *= corr;
                p0[qq] = e0; p1[qq] = e1;
            }
            #pragma unroll
            for (int qq = 0; qq < 4; ++qq) {
                *(u16*)(Pb + (g * 4 + qq) * 80 + li * 2)        = f2h(p0[qq]);
                *(u16*)(Pb + (g * 4 + qq) * 80 + (16 + li) * 2) = f2h(p1[qq]);
            }
            h8v pf  = *(const h8v*)(Pb + li * 80 + g * 16);
            h8v vf0 = *(const h8v*)(lds + 20480 + li * 528        + kb * 2 + g * 16);
            h8v vf1 = *(const h8v*)(lds + 20480 + (16 + li) * 528 + kb * 2 + g * 16);
            o0 = __builtin_amdgcn_mfma_f32_16x16x32_f16(pf, vf0, o0, 0, 0, 0);
            o1 = __builtin_amdgcn_mfma_f32_16x16x32_f16(pf, vf1, o1, 0, 0, 0);
        }
        float invs[4] = {1.f / lrun0, 1.f / lrun1, 1.f / lrun2, 1.f / lrun3};
        #pragma unroll
        for (int qq = 0; qq < 4; ++qq) {
            int tok = mq + g * 4 + qq;
            int rIn = tok & 127;
            size_t tb = ((size_t)(b * 2 + (tok >> 7)) * 4 + (h >> 1)) * 8192;
            float f0 = o0[qq] * invs[qq];
            float f1 = o1[qq] * invs[qq];
            int kIn0 = (h & 1) * 32 + li;
            int kIn1 = kIn0 + 16;
            int ub0 = rIn * 64 + (((kIn0 >> 3) ^ (rIn & 7)) << 3) + (kIn0 & 7);
            int ub1 = rIn * 64 + (((kIn1 >> 3) ^ (rIn & 7)) << 3) + (kIn1 & 7);
            outT[tb + ub0] = f2h(f0);
            outT[tb + ub1] = f2h(f1);
        }
    }
}

// ---------------- loss ----------------
__global__ __launch_bounds__(256)
void loss_kernel(const float* __restrict__ lg, const int* __restrict__ tgt,
                 float* __restrict__ loss) {
    int row = blockIdx.x * 256 + threadIdx.x;
    const float* r = lg + (size_t)row * VV;
    float mx = -INFINITY;
    for (int v = 0; v < VV; ++v) mx = fmaxf(mx, r[v]);
    float se = 0.f;
    for (int v = 0; v < VV; ++v) se += __expf(r[v] - mx);
    float nl = mx + __logf(se) - r[tgt[row]];
    #pragma unroll
    for (int m = 1; m < 64; m <<= 1) nl += __shfl_xor(nl, m, 64);
    __shared__ float wsum[4];
    int lane = threadIdx.x & 63, wv = threadIdx.x >> 6;
    if (lane == 0) wsum[wv] = nl;
    __syncthreads();
    if (threadIdx.x == 0)
        atomicAdd(loss, (wsum[0] + wsum[1] + wsum[2] + wsum[3]) * (1.f / BT));
}

extern "C" void kernel_launch(void* const* d_in, const int* in_sizes, int n_in,
                              void* d_out, int out_size, void* d_ws, size_t ws_size,
                              hipStream_t stream) {
    const int*   idx  = (const int*)d_in[0];
    const int*   tgt  = (const int*)d_in[1];
    const float* te   = (const float*)d_in[2];
    const float* pe   = (const float*)d_in[3];
    const float* wq   = (const float*)d_in[4];
    const float* bq   = (const float*)d_in[5];
    const float* wk   = (const float*)d_in[6];
    const float* bk   = (const float*)d_in[7];
    const float* wv   = (const float*)d_in[8];
    const float* bv   = (const float*)d_in[9];
    const float* wo   = (const float*)d_in[10];
    const float* bo   = (const float*)d_in[11];
    const float* ln1g = (const float*)d_in[12];
    const float* ln1b = (const float*)d_in[13];
    const float* w1   = (const float*)d_in[14];
    const float* b1   = (const float*)d_in[15];
    const float* w2   = (const float*)d_in[16];
    const float* b2   = (const float*)d_in[17];
    const float* ln2g = (const float*)d_in[18];
    const float* ln2b = (const float*)d_in[19];
    const float* lnfg = (const float*)d_in[20];
    const float* lnfb = (const float*)d_in[21];
    const float* lmw  = (const float*)d_in[22];
    const float* lmb  = (const float*)d_in[23];
    float* out = (float*)d_out;

    // workspace layout (bytes)
    char* base = (char*)d_ws;
    float* x       = (float*)(base);                       // 16 MB fp32 residual
    u16*   qkvh    = (u16*)  (base + (16ll << 20));        // 24 MB fp16 [16384][768]
    u16*   hiddenT = (u16*)  (base + (40ll << 20));        // 32 MB fp16 tiled
    u16*   xnT     = (u16*)  (base + (72ll << 20));        //  8 MB fp16 tiled
    u16*   qkvT    = (u16*)  (base + (80ll << 20));        //  2.25 MB
    u16*   woT     = (u16*)  (base + (83ll << 20));        //  0.75 MB
    u16*   w1T     = (u16*)  (base + (84ll << 20));        //  3 MB
    u16*   w2T     = (u16*)  (base + (87ll << 20));        //  3 MB
    u16*   lmT     = (u16*)  (base + (90ll << 20));        //  64 KB
    float* Bp      = (float*)(base + (91ll << 20));        //  18 KB
    float* Pbuf    = (float*)(base + (96ll << 20));        // 32 MB (proj partials x2)
    float* Qbuf    = (float*)(base + (128ll << 20));       // 32 MB (w2 partials x2)

    pack_all<<<dim3(E_TOT / 256), 256, 0, stream>>>(wq, wk, wv, wo, w1, w2, lmw,
                                                    bq, bk, bv,
                                                    qkvT, woT, w1T, w2T, lmT, Bp);
    embed_kernel<<<dim3((BT * 64) / 256), 256, 0, stream>>>(idx, te, pe, x);

    for (int l = 0; l < LL; ++l) {
        if (l == 0)
            ln_kernel<<<dim3(BT / 4), 256, 0, stream>>>(x, ln1g, ln1b, xnT);
        else
            sum_ln<<<dim3(BT / 4), 256, 0, stream>>>(x, Qbuf, Qbuf + (size_t)BT * CC,
                                                     b2 + (l - 1) * CC,
                                                     ln1g + l * CC, ln1b + l * CC, xnT);
        gemm_mfma<0><<<dim3(128 * 6, 1), 512, 0, stream>>>(
            xnT, qkvT + (size_t)l * 196608, Bp + l * 768, nullptr, qkvh, 4, 4, 6, 768, 0);
        attn_mfma<<<dim3(BB * HH), 256, 0, stream>>>(qkvh, xnT);
        gemm_mfma<4><<<dim3(128 * 2, 2), 512, 0, stream>>>(
            xnT, woT + (size_t)l * 65536, nullptr, Pbuf, nullptr, 4, 2, 2, 256, 0);
        sum_ln<<<dim3(BT / 4), 256, 0, stream>>>(x, Pbuf, Pbuf + (size_t)BT * CC,
                                                 bo + l * CC,
                                                 ln2g + l * CC, ln2b + l * CC, xnT);
        gemm_mfma<2><<<dim3(128 * 8, 1), 512, 0, stream>>>(
            xnT, w1T + (size_t)l * 262144, b1 + l * 1024, nullptr, hiddenT, 4, 4, 8, 1024, 16);
        gemm_mfma<4><<<dim3(128 * 2, 2), 512, 0, stream>>>(
            hiddenT, w2T + (size_t)l * 262144, nullptr, Qbuf, nullptr, 16, 8, 2, 256, 0);
    }
    sum_ln<<<dim3(BT / 4), 256, 0, stream>>>(x, Qbuf, Qbuf + (size_t)BT * CC,
                                             b2 + (LL - 1) * CC, lnfg, lnfb, xnT);
    gemm_mfma<3><<<dim3(128 * 1, 1), 512, 0, stream>>>(
        xnT, lmT, lmb, out, nullptr, 4, 4, 1, VV, 0);

    hipMemsetAsync(out + (size_t)BT * VV, 0, sizeof(float), stream);
    loss_kernel<<<dim3(BT / 256), 256, 0, stream>>>(out, tgt, out + (size_t)BT * VV);
}

// Round 13
// 786.060 us; speedup vs baseline: 3.0054x; 1.0390x over previous
//
#include <hip/hip_runtime.h>
#include <hip/hip_bf16.h>
#include <math.h>

#define BB 64
#define TT 256
#define CC 256
#define VV 65
#define LL 6
#define HH 8
#define BT (BB*TT)   // 16384

typedef unsigned short u16;
typedef __attribute__((ext_vector_type(8))) _Float16 h8v;   // 8 fp16 (4 VGPRs)
typedef __attribute__((ext_vector_type(4))) float f4v;      // MFMA acc
typedef __attribute__((ext_vector_type(4))) unsigned short u16x4;

typedef const unsigned int __attribute__((address_space(1))) gu32;
typedef unsigned int       __attribute__((address_space(3))) lu32;

__device__ inline u16 f2h(float f) { _Float16 h = (_Float16)f; return *(u16*)&h; }
__device__ inline float h2f(u16 h) { _Float16 x = *(_Float16*)&h; return (float)x; }

__device__ inline void gld_lds16(const void* g, void* l) {
    __builtin_amdgcn_global_load_lds((gu32*)g, (lu32*)l, 16, 0, 0);
}

// Tiled operand format: matrix [R, K] -> tiles [R/128][K/64]; tile = 16384 B
// fp16, swizzled: element (r,k) at ushort index r*64 + ((k>>3)^(r&7))*8 + (k&7).

// ---------------- one-shot pack of ALL weights ----------------
__device__ inline void pack_dev(const float* __restrict__ src, u16* __restrict__ dst,
                                int K, int N, int NT, int KT, int id) {
    int perLayer = NT * KT * 8192;
    int l = id / perLayer; int rem = id - l * perLayer;
    int tile = rem >> 13, within = rem & 8191;
    int nT = tile / KT, kT = tile - nT * KT;
    int colIn = within >> 6, u = within & 63;
    int s = (u >> 3) ^ (colIn & 7);
    int k = kT * 64 + s * 8 + (u & 7);
    int n = nT * 128 + colIn;
    float v = (n < N) ? src[((size_t)l * K + k) * N + n] : 0.f;
    dst[((size_t)l * NT * KT + tile) * 8192 + within] = f2h(v);
}

#define E_QKV (LL*24*8192)
#define E_WO  (LL*8*8192)
#define E_W1  (LL*32*8192)
#define E_W2  (LL*32*8192)
#define E_LM  (4*8192)
#define E_QB  (LL*768)
#define E_TOT (E_QKV+E_WO+E_W1+E_W2+E_LM+E_QB)   // 4,755,968 = 256*18578

__global__ __launch_bounds__(256)
void pack_all(const float* __restrict__ wq, const float* __restrict__ wk,
              const float* __restrict__ wv, const float* __restrict__ wo,
              const float* __restrict__ w1, const float* __restrict__ w2,
              const float* __restrict__ lmw,
              const float* __restrict__ bq, const float* __restrict__ bk,
              const float* __restrict__ bv,
              u16* __restrict__ qkvT, u16* __restrict__ woT, u16* __restrict__ w1T,
              u16* __restrict__ w2T, u16* __restrict__ lmT, float* __restrict__ Bp) {
    int id = blockIdx.x * 256 + threadIdx.x;
    if (id < E_QKV) {
        const int perLayer = 24 * 8192;
        int l = id / perLayer; int rem = id - l * perLayer;
        int tile = rem >> 13, within = rem & 8191;
        int nT = tile >> 2, kT = tile & 3;
        int colIn = within >> 6, u = within & 63;
        int s = (u >> 3) ^ (colIn & 7);
        int k = kT * 64 + s * 8 + (u & 7);
        int n = nT * 128 + colIn;
        int which = n >> 8, hd = n & 255, h = hd >> 5, d = hd & 31;
        const float* src = (which == 0) ? wq : (which == 1) ? wk : wv;
        float v = src[(((size_t)l * HH + h) * CC + k) * 32 + d];
        if (which == 0) v *= 0.0625f;   // fold attention scale C^-0.5 = 1/16 into Wq
        qkvT[((size_t)l * 24 + tile) * 8192 + within] = f2h(v);
        return;
    }
    id -= E_QKV;
    if (id < E_WO) { pack_dev(wo, woT, 256, 256, 2, 4, id); return; }
    id -= E_WO;
    if (id < E_W1) { pack_dev(w1, w1T, 256, 1024, 8, 4, id); return; }
    id -= E_W1;
    if (id < E_W2) { pack_dev(w2, w2T, 1024, 256, 2, 16, id); return; }
    id -= E_W2;
    if (id < E_LM) { pack_dev(lmw, lmT, 256, VV, 1, 4, id); return; }
    id -= E_LM;
    if (id < E_QB) {
        int l = id / 768, j = id % 768;
        int which = j >> 8, hd = j & 255, h = hd >> 5, d = hd & 31;
        const float* src = (which == 0) ? bq : (which == 1) ? bk : bv;
        float v = src[((size_t)l * HH + h) * 32 + d];
        if (which == 0) v *= 0.0625f;   // fold scale into bq too
        Bp[id] = v;
    }
}

// ---------------- embedding ----------------
__global__ __launch_bounds__(256)
void embed_kernel(const int* __restrict__ idx, const float* __restrict__ te,
                  const float* __restrict__ pe, float* __restrict__ x) {
    int i = blockIdx.x * blockDim.x + threadIdx.x;
    if (i >= BT * 64) return;
    int bt = i >> 6, c4 = i & 63;
    int tok = idx[bt];
    int t = bt & (TT - 1);
    float4 a = ((const float4*)te)[(size_t)tok * 64 + c4];
    float4 p = ((const float4*)pe)[(size_t)t * 64 + c4];
    float4 o; o.x = a.x + p.x; o.y = a.y + p.y; o.z = a.z + p.z; o.w = a.w + p.w;
    ((float4*)x)[i] = o;
}

// ---------------- LN core (shared by ln_kernel / sum_ln) ----------------
__device__ inline void ln_emit(float4 v, const float* __restrict__ g,
                               const float* __restrict__ b, u16* __restrict__ outT,
                               int row, int lane) {
    float s = v.x + v.y + v.z + v.w;
    #pragma unroll
    for (int m = 1; m < 64; m <<= 1) s += __shfl_xor(s, m, 64);
    float mu = s * (1.f / CC);
    float dx = v.x - mu, dy = v.y - mu, dz = v.z - mu, dw = v.w - mu;
    float vs = dx * dx + dy * dy + dz * dz + dw * dw;
    #pragma unroll
    for (int m = 1; m < 64; m <<= 1) vs += __shfl_xor(vs, m, 64);
    float rs = rsqrtf(vs * (1.f / CC) + 1e-5f);
    float4 gv = ((const float4*)g)[lane];
    float4 bv = ((const float4*)b)[lane];
    int rIn = row & 127, mT = row >> 7;
    int kT = lane >> 4;
    int kIn = (lane * 4) & 63;
    int slot = kIn >> 3, j = kIn & 7;
    size_t base = ((size_t)mT * 4 + kT) * 8192;
    int ub = rIn * 64 + ((slot ^ (rIn & 7)) << 3) + j;
    u16x4 hv;
    hv[0] = f2h(dx * rs * gv.x + bv.x);
    hv[1] = f2h(dy * rs * gv.y + bv.y);
    hv[2] = f2h(dz * rs * gv.z + bv.z);
    hv[3] = f2h(dw * rs * gv.w + bv.w);
    *(u16x4*)(outT + base + ub) = hv;
}

// plain LN (layer-0 ln1): x already complete
__global__ __launch_bounds__(256)
void ln_kernel(const float* __restrict__ x, const float* __restrict__ g,
               const float* __restrict__ b, u16* __restrict__ outT) {
    int lane = threadIdx.x & 63;
    int row = blockIdx.x * 4 + (threadIdx.x >> 6);
    float4 v = ((const float4*)(x + (size_t)row * CC))[lane];
    ln_emit(v, g, b, outT, row, lane);
}

// fused: xs = x + p0 + p1 + gemm_bias (p0/p1 fp16); x <- xs; outT <- LN(xs) tiled
__global__ __launch_bounds__(256)
void sum_ln(float* __restrict__ x, const u16* __restrict__ p0,
            const u16* __restrict__ p1, const float* __restrict__ gbias,
            const float* __restrict__ g, const float* __restrict__ b,
            u16* __restrict__ outT) {
    int lane = threadIdx.x & 63;
    int row = blockIdx.x * 4 + (threadIdx.x >> 6);
    size_t off = (size_t)row * CC;
    float4 v  = ((const float4*)(x + off))[lane];
    u16x4 a0 = ((const u16x4*)(p0 + off))[lane];
    u16x4 a1 = ((const u16x4*)(p1 + off))[lane];
    float4 bb = ((const float4*)gbias)[lane];
    v.x += h2f(a0[0]) + h2f(a1[0]) + bb.x;
    v.y += h2f(a0[1]) + h2f(a1[1]) + bb.y;
    v.z += h2f(a0[2]) + h2f(a1[2]) + bb.z;
    v.w += h2f(a0[3]) + h2f(a1[3]) + bb.w;
    ((float4*)(x + off))[lane] = v;
    ln_emit(v, g, b, outT, row, lane);
}

// ---------------- MFMA GEMM: C[16384,N] = A @ W (A,B tiled fp16) --------------
// BM=128 BN=128 BK=64, 512 thr = 8 waves (4x2, wave tile 32x64), dbuf prefetch.
// EPI 0: fp16 row-major + bias | 2: bias+relu -> tiled fp16 | 3: N=65 fp32
// EPI 4: split-K partial -> fp16 store into CoT + blockIdx.y*BT*N (no bias)
template<int EPI>
__global__ __launch_bounds__(512, 4)
void gemm_mfma(const u16* __restrict__ At, const u16* __restrict__ Bt,
               const float* __restrict__ bias, float* __restrict__ Co,
               u16* __restrict__ CoT, int KTfull, int KTc, int NT, int N, int KTout) {
    __shared__ __align__(16) char lds[65536];   // 2 bufs x (A 16K + B 16K)
    int tid = threadIdx.x;
    int l = tid & 63, w = tid >> 6;             // 8 waves
    int nwg = gridDim.x;
    int id = blockIdx.x;
    int cpx = nwg >> 3;                          // all grids %8==0
    id = (id & 7) * cpx + (id >> 3);             // XCD-contiguous chunks
    int mT = id / NT, nT = id - mT * NT;
    int ktBase = blockIdx.y * KTc;

    const char* Abase = (const char*)(At + ((size_t)mT * KTfull + ktBase) * 8192);
    const char* Bbase = (const char*)(Bt + ((size_t)nT * KTfull + ktBase) * 8192);
    int wm = w >> 1, wn = w & 1;                 // wave tile: rows [wm*32,+32), cols [wn*64,+64)

    f4v acc[2][4];
    #pragma unroll
    for (int i = 0; i < 2; ++i)
        #pragma unroll
        for (int j = 0; j < 4; ++j) acc[i][j] = (f4v)0.f;

    int lrow = l & 15, lg = l >> 4;

    #define STAGE(buf, kt) {                                           \
        char* la = lds + (buf) * 32768 + w * 2048;                     \
        char* lb = lds + (buf) * 32768 + 16384 + w * 2048;             \
        const char* ga = Abase + (kt) * 16384 + w * 2048 + l * 16;     \
        const char* gb = Bbase + (kt) * 16384 + w * 2048 + l * 16;     \
        _Pragma("unroll")                                              \
        for (int j = 0; j < 2; ++j) {                                  \
            gld_lds16(ga + j * 1024, la + j * 1024);                   \
            gld_lds16(gb + j * 1024, lb + j * 1024);                   \
        } }

    STAGE(0, 0);
    __syncthreads();
    int cur = 0;
    for (int kt = 0; kt < KTc; ++kt) {
        if (kt + 1 < KTc) STAGE(cur ^ 1, kt + 1);   // prefetch overlaps compute
        const char* lb0 = lds + cur * 32768;
        #pragma unroll
        for (int kh = 0; kh < 2; ++kh) {
            h8v ah[2], bh[4];
            #pragma unroll
            for (int mi = 0; mi < 2; ++mi) {
                int rc = wm * 32 + mi * 16 + lrow;
                ah[mi] = *(const h8v*)(lb0 + rc * 128 + 16 * ((kh * 4 + lg) ^ (rc & 7)));
            }
            #pragma unroll
            for (int ni = 0; ni < 4; ++ni) {
                int rc = wn * 64 + ni * 16 + lrow;
                bh[ni] = *(const h8v*)(lb0 + 16384 + rc * 128 + 16 * ((kh * 4 + lg) ^ (rc & 7)));
            }
            #pragma unroll
            for (int mi = 0; mi < 2; ++mi)
                #pragma unroll
                for (int ni = 0; ni < 4; ++ni)
                    acc[mi][ni] = __builtin_amdgcn_mfma_f32_16x16x32_f16(ah[mi], bh[ni], acc[mi][ni], 0, 0, 0);
        }
        __syncthreads();
        cur ^= 1;
    }
    #undef STAGE

    // epilogue: C frag col = l&15, row = (l>>4)*4 + q  [m89-verified]
    int colbase = nT * 128 + wn * 64;
    if (EPI == 0) {          // fp16 row-major [16384][N] + bias
        #pragma unroll
        for (int mi = 0; mi < 2; ++mi) {
            int r0 = mT * 128 + wm * 32 + mi * 16 + lg * 4;
            #pragma unroll
            for (int ni = 0; ni < 4; ++ni) {
                int cg = colbase + ni * 16 + lrow;
                float bv = bias[cg];
                #pragma unroll
                for (int q = 0; q < 4; ++q)
                    CoT[(size_t)(r0 + q) * N + cg] = f2h(acc[mi][ni][q] + bv);
            }
        }
    } else if (EPI == 2) {   // bias + relu -> tiled fp16
        #pragma unroll
        for (int mi = 0; mi < 2; ++mi) {
            int r0 = mT * 128 + wm * 32 + mi * 16 + lg * 4;
            #pragma unroll
            for (int ni = 0; ni < 4; ++ni) {
                int cg = colbase + ni * 16 + lrow;
                float bv = bias[cg];
                int kTo = cg >> 6, kIn = cg & 63;
                size_t tbase = ((size_t)mT * KTout + kTo) * 8192;
                #pragma unroll
                for (int q = 0; q < 4; ++q) {
                    int rIn = (r0 + q) & 127;
                    float f = fmaxf(acc[mi][ni][q] + bv, 0.f);
                    int ub = rIn * 64 + (((kIn >> 3) ^ (rIn & 7)) << 3) + (kIn & 7);
                    CoT[tbase + ub] = f2h(f);
                }
            }
        }
    } else if (EPI == 3) {   // lm head fp32 [16384][65]
        #pragma unroll
        for (int mi = 0; mi < 2; ++mi) {
            int r0 = mT * 128 + wm * 32 + mi * 16 + lg * 4;
            #pragma unroll
            for (int ni = 0; ni < 4; ++ni) {
                int cg = colbase + ni * 16 + lrow;
                if (cg < VV) {
                    float bv = bias[cg];
                    #pragma unroll
                    for (int q = 0; q < 4; ++q)
                        Co[(size_t)(r0 + q) * VV + cg] = acc[mi][ni][q] + bv;
                }
            }
        }
    } else {                 // EPI 4: fp16 partial store (no bias, no atomic)
        u16* P = CoT + (size_t)blockIdx.y * ((size_t)BT * N);
        #pragma unroll
        for (int mi = 0; mi < 2; ++mi) {
            int r0 = mT * 128 + wm * 32 + mi * 16 + lg * 4;
            #pragma unroll
            for (int ni = 0; ni < 4; ++ni) {
                int cg = colbase + ni * 16 + lrow;
                #pragma unroll
                for (int q = 0; q < 4; ++q)
                    P[(size_t)(r0 + q) * N + cg] = f2h(acc[mi][ni][q]);
            }
        }
    }
}

// ---------------- MFMA flash attention: block per (b,h), 4 waves ----------------
// qkv input fp16 row-major [16384][768]; Q pre-scaled by 1/16 at weight pack.
// LDS: K fp16 [256][80B] @0 ; V^T fp16 [32][528B] @20480 ; P/wave [16][80B] @37376+w*1280.
__global__ __launch_bounds__(256)
void attn_mfma(const u16* __restrict__ qkv, u16* __restrict__ outT) {
    __shared__ __align__(16) char lds[42496];
    int bh = blockIdx.x;
    bh = (bh & 7) * 64 + (bh >> 3);      // bijective XCD swizzle (512 = 8*64)
    int b = bh >> 3, h = bh & 7;
    const u16* base = qkv + (size_t)b * TT * 768;
    int tid = threadIdx.x;
    int w = tid >> 6, l = tid & 63;
    int li = l & 15, g = l >> 4;

    {
        int r0 = tid >> 3, c = tid & 7;
        #pragma unroll
        for (int it = 0; it < 8; ++it) {
            int t = it * 32 + r0;
            u16x4 kv = *(const u16x4*)(base + (size_t)t * 768 + 256 + h * 32 + c * 4);
            u16x4 vv = *(const u16x4*)(base + (size_t)t * 768 + 512 + h * 32 + c * 4);
            *(u16x4*)(lds + t * 80 + c * 8) = kv;
            *(u16*)(lds + 20480 + (c * 4 + 0) * 528 + t * 2) = vv[0];
            *(u16*)(lds + 20480 + (c * 4 + 1) * 528 + t * 2) = vv[1];
            *(u16*)(lds + 20480 + (c * 4 + 2) * 528 + t * 2) = vv[2];
            *(u16*)(lds + 20480 + (c * 4 + 3) * 528 + t * 2) = vv[3];
        }
    }
    __syncthreads();

    char* Pb = lds + 37376 + w * 1280;
    int mts[4] = {w, 7 - w, 8 + w, 15 - w};
    #pragma unroll
    for (int im = 0; im < 4; ++im) {
        int mt = mts[im];
        int mq = mt * 16;
        h8v aq = *(const h8v*)(base + (size_t)(mq + li) * 768 + h * 32 + g * 8);

        f4v o0 = (f4v)0.f, o1 = (f4v)0.f;
        float mrun0 = -1e30f, mrun1 = -1e30f, mrun2 = -1e30f, mrun3 = -1e30f;
        float lrun0 = 0.f, lrun1 = 0.f, lrun2 = 0.f, lrun3 = 0.f;
        int nu = (mt >> 1) + 1;
        for (int kt = 0; kt < nu; ++kt) {
            int kb = kt * 32;
            h8v kf0 = *(const h8v*)(lds + (kb + li) * 80 + g * 16);
            h8v kf1 = *(const h8v*)(lds + (kb + 16 + li) * 80 + g * 16);
            f4v s0 = __builtin_amdgcn_mfma_f32_16x16x32_f16(aq, kf0, (f4v)0.f, 0, 0, 0);
            f4v s1 = __builtin_amdgcn_mfma_f32_16x16x32_f16(aq, kf1, (f4v)0.f, 0, 0, 0);
            bool maskunit = (kt == nu - 1);
            float p0[4], p1[4];
            float* mr[4] = {&mrun0, &mrun1, &mrun2, &mrun3};
            float* lr[4] = {&lrun0, &lrun1, &lrun2, &lrun3};
            #pragma unroll
            for (int qq = 0; qq < 4; ++qq) {
                float v0 = s0[qq];               // scale pre-folded into Wq/bq
                float v1 = s1[qq];
                if (maskunit) {
                    int qg = mq + g * 4 + qq;
                    if (kb + li > qg)      v0 = -1e30f;
                    if (kb + 16 + li > qg) v1 = -1e30f;
                }
                float tm = fmaxf(v0, v1);
                #pragma unroll
                for (int msk = 1; msk < 16; msk <<= 1)
                    tm = fmaxf(tm, __shfl_xor(tm, msk, 64));
                float mold = *mr[qq];
                float mnew = fmaxf(mold, tm);
                float corr = __expf(mold - mnew);
                float e0 = __expf(v0 - mnew);
                float e1 = __expf(v1 - mnew);
                float ts = e0 + e1;
                #pragma unroll
                for (int msk = 1; msk < 16; msk <<= 1)
                    ts += __shfl_xor(ts, msk, 64);
                *lr[qq] = *lr[qq] * corr + ts;
                *mr[qq] = mnew;
                o0[qq] *= corr; o1[qq] *= corr;
                p0[qq] = e0; p1[qq] = e1;
            }
            #pragma unroll
            for (int qq = 0; qq < 4; ++qq) {
                *(u16*)(Pb + (g * 4 + qq) * 80 + li * 2)        = f2h(p0[qq]);
                *(u16*)(Pb + (g * 4 + qq) * 80 + (16 + li) * 2) = f2h(p1[qq]);
            }
            h8v pf  = *(const h8v*)(Pb + li * 80 + g * 16);
            h8v vf0 = *(const h8v*)(lds + 20480 + li * 528        + kb * 2 + g * 16);
            h8v vf1 = *(const h8v*)(lds + 20480 + (16 + li) * 528 + kb * 2 + g * 16);
            o0 = __builtin_amdgcn_mfma_f32_16x16x32_f16(pf, vf0, o0, 0, 0, 0);
            o1 = __builtin_amdgcn_mfma_f32_16x16x32_f16(pf, vf1, o1, 0, 0, 0);
        }
        float invs[4] = {1.f / lrun0, 1.f / lrun1, 1.f / lrun2, 1.f / lrun3};
        #pragma unroll
        for (int qq = 0; qq < 4; ++qq) {
            int tok = mq + g * 4 + qq;
            int rIn = tok & 127;
            size_t tb = ((size_t)(b * 2 + (tok >> 7)) * 4 + (h >> 1)) * 8192;
            float f0 = o0[qq] * invs[qq];
            float f1 = o1[qq] * invs[qq];
            int kIn0 = (h & 1) * 32 + li;
            int kIn1 = kIn0 + 16;
            int ub0 = rIn * 64 + (((kIn0 >> 3) ^ (rIn & 7)) << 3) + (kIn0 & 7);
            int ub1 = rIn * 64 + (((kIn1 >> 3) ^ (rIn & 7)) << 3) + (kIn1 & 7);
            outT[tb + ub0] = f2h(f0);
            outT[tb + ub1] = f2h(f1);
        }
    }
}

// ---------------- loss ----------------
__global__ __launch_bounds__(256)
void loss_kernel(const float* __restrict__ lg, const int* __restrict__ tgt,
                 float* __restrict__ loss) {
    int row = blockIdx.x * 256 + threadIdx.x;
    const float* r = lg + (size_t)row * VV;
    float mx = -INFINITY;
    for (int v = 0; v < VV; ++v) mx = fmaxf(mx, r[v]);
    float se = 0.f;
    for (int v = 0; v < VV; ++v) se += __expf(r[v] - mx);
    float nl = mx + __logf(se) - r[tgt[row]];
    #pragma unroll
    for (int m = 1; m < 64; m <<= 1) nl += __shfl_xor(nl, m, 64);
    __shared__ float wsum[4];
    int lane = threadIdx.x & 63, wv = threadIdx.x >> 6;
    if (lane == 0) wsum[wv] = nl;
    __syncthreads();
    if (threadIdx.x == 0)
        atomicAdd(loss, (wsum[0] + wsum[1] + wsum[2] + wsum[3]) * (1.f / BT));
}

extern "C" void kernel_launch(void* const* d_in, const int* in_sizes, int n_in,
                              void* d_out, int out_size, void* d_ws, size_t ws_size,
                              hipStream_t stream) {
    const int*   idx  = (const int*)d_in[0];
    const int*   tgt  = (const int*)d_in[1];
    const float* te   = (const float*)d_in[2];
    const float* pe   = (const float*)d_in[3];
    const float* wq   = (const float*)d_in[4];
    const float* bq   = (const float*)d_in[5];
    const float* wk   = (const float*)d_in[6];
    const float* bk   = (const float*)d_in[7];
    const float* wv   = (const float*)d_in[8];
    const float* bv   = (const float*)d_in[9];
    const float* wo   = (const float*)d_in[10];
    const float* bo   = (const float*)d_in[11];
    const float* ln1g = (const float*)d_in[12];
    const float* ln1b = (const float*)d_in[13];
    const float* w1   = (const float*)d_in[14];
    const float* b1   = (const float*)d_in[15];
    const float* w2   = (const float*)d_in[16];
    const float* b2   = (const float*)d_in[17];
    const float* ln2g = (const float*)d_in[18];
    const float* ln2b = (const float*)d_in[19];
    const float* lnfg = (const float*)d_in[20];
    const float* lnfb = (const float*)d_in[21];
    const float* lmw  = (const float*)d_in[22];
    const float* lmb  = (const float*)d_in[23];
    float* out = (float*)d_out;

    // workspace layout (bytes)
    char* base = (char*)d_ws;
    float* x       = (float*)(base);                       // 16 MB fp32 residual
    u16*   qkvh    = (u16*)  (base + (16ll << 20));        // 24 MB fp16 [16384][768]
    u16*   hiddenT = (u16*)  (base + (40ll << 20));        // 32 MB fp16 tiled
    u16*   xnT     = (u16*)  (base + (72ll << 20));        //  8 MB fp16 tiled
    u16*   qkvT    = (u16*)  (base + (80ll << 20));        //  2.25 MB
    u16*   woT     = (u16*)  (base + (83ll << 20));        //  0.75 MB
    u16*   w1T     = (u16*)  (base + (84ll << 20));        //  3 MB
    u16*   w2T     = (u16*)  (base + (87ll << 20));        //  3 MB
    u16*   lmT     = (u16*)  (base + (90ll << 20));        //  64 KB
    float* Bp      = (float*)(base + (91ll << 20));        //  18 KB
    u16*   Pbuf    = (u16*)  (base + (96ll << 20));        // 16 MB (proj partials x2, fp16)
    u16*   Qbuf    = (u16*)  (base + (112ll << 20));       // 16 MB (w2 partials x2, fp16)

    pack_all<<<dim3(E_TOT / 256), 256, 0, stream>>>(wq, wk, wv, wo, w1, w2, lmw,
                                                    bq, bk, bv,
                                                    qkvT, woT, w1T, w2T, lmT, Bp);
    embed_kernel<<<dim3((BT * 64) / 256), 256, 0, stream>>>(idx, te, pe, x);

    for (int l = 0; l < LL; ++l) {
        if (l == 0)
            ln_kernel<<<dim3(BT / 4), 256, 0, stream>>>(x, ln1g, ln1b, xnT);
        else
            sum_ln<<<dim3(BT / 4), 256, 0, stream>>>(x, Qbuf, Qbuf + (size_t)BT * CC,
                                                     b2 + (l - 1) * CC,
                                                     ln1g + l * CC, ln1b + l * CC, xnT);
        gemm_mfma<0><<<dim3(128 * 6, 1), 512, 0, stream>>>(
            xnT, qkvT + (size_t)l * 196608, Bp + l * 768, nullptr, qkvh, 4, 4, 6, 768, 0);
        attn_mfma<<<dim3(BB * HH), 256, 0, stream>>>(qkvh, xnT);
        gemm_mfma<4><<<dim3(128 * 2, 2), 512, 0, stream>>>(
            xnT, woT + (size_t)l * 65536, nullptr, nullptr, Pbuf, 4, 2, 2, 256, 0);
        sum_ln<<<dim3(BT / 4), 256, 0, stream>>>(x, Pbuf, Pbuf + (size_t)BT * CC,
                                                 bo + l * CC,
                                                 ln2g + l * CC, ln2b + l * CC, xnT);
        gemm_mfma<2><<<dim3(128 * 8, 1), 512, 0, stream>>>(
            xnT, w1T + (size_t)l * 262144, b1 + l * 1024, nullptr, hiddenT, 4, 4, 8, 1024, 16);
        gemm_mfma<4><<<dim3(128 * 2, 2), 512, 0, stream>>>(
            hiddenT, w2T + (size_t)l * 262144, nullptr, nullptr, Qbuf, 16, 8, 2, 256, 0);
    }
    sum_ln<<<dim3(BT / 4), 256, 0, stream>>>(x, Qbuf, Qbuf + (size_t)BT * CC,
                                             b2 + (LL - 1) * CC, lnfg, lnfb, xnT);
    gemm_mfma<3><<<dim3(128 * 1, 1), 512, 0, stream>>>(
        xnT, lmT, lmb, out, nullptr, 4, 4, 1, VV, 0);

    hipMemsetAsync(out + (size_t)BT * VV, 0, sizeof(float), stream);
    loss_kernel<<<dim3(BT / 256), 256, 0, stream>>>(out, tgt, out + (size_t)BT * VV);
}